// Round 3
// baseline (250.645 us; speedup 1.0000x reference)
//
#include <hip/hip_runtime.h>
#include <math.h>

// Problem constants
#define B64 64
#define IN_SH 10000
#define GOSLD 10240         // gos bf16 padded leading dim (zero pad), mult of 32
#define EXP_SH 53
#define HID 1500
#define NPAD1 1536          // padded N for gemm1 partials
#define NBC 2048
#define K2 1553
#define XLD 1664            // X bf16 padded leading dim, covers max prefetch read
#define KS1 40              // split-K chunks gemm1
#define KCH1 256            // k per chunk (8 steps of 32)
#define KST1 8
#define KS2 13
#define KCH2 128            // 4 steps of 32
#define KST2 4
#define CMCH 32             // colmax row chunks

using short8  = __attribute__((ext_vector_type(8))) short;
using floatx4 = __attribute__((ext_vector_type(4))) float;
using uintx4  = __attribute__((ext_vector_type(4))) unsigned int;

__device__ __forceinline__ unsigned short f2bf(float f) {
    unsigned u = __float_as_uint(f);
    u += 0x7fffu + ((u >> 16) & 1u);   // RNE
    return (unsigned short)(u >> 16);
}

// Fused: [0,320) gos fp32->bf16 pad; [320,576) hpo partial column max (no atomics)
__global__ __launch_bounds__(256) void pre_k(const float* __restrict__ g,
                                             unsigned short* __restrict__ gb,
                                             const float* __restrict__ M,
                                             float* __restrict__ cm) {
    int bi = blockIdx.x;
    if (bi < 320) {
        int idx = bi * 256 + threadIdx.x;          // 64*1280 threads
        int b = idx / (GOSLD / 8);
        int k = (idx % (GOSLD / 8)) * 8;
        unsigned int o[4] = {0u, 0u, 0u, 0u};
        if (k < IN_SH) {
            const float* p = g + (size_t)b * IN_SH + k;
            #pragma unroll
            for (int i = 0; i < 4; i++) {
                float lo = p[2 * i], hi = p[2 * i + 1];
                o[i] = (unsigned)f2bf(lo) | ((unsigned)f2bf(hi) << 16);
            }
        }
        uintx4 v; v.x = o[0]; v.y = o[1]; v.z = o[2]; v.w = o[3];
        *(uintx4*)(gb + (size_t)b * GOSLD + k) = v;
    } else {
        int ci = bi - 320;                          // 256 blocks: 8 j-tiles x 32 row-chunks
        int j  = (ci & 7) * 256 + threadIdx.x;      // 0..2047
        int i0 = (ci >> 3) * 64;
        float m = 0.0f;
        #pragma unroll 16
        for (int i = i0; i < i0 + 64; i++)
            m = fmaxf(m, M[(size_t)i * NBC + j]);
        cm[(ci >> 3) * NBC + j] = m;
    }
}

// one pipeline stage's loads: W column slice (fp32, strided) + activation rows (bf16 x8)
__device__ __forceinline__ void load_step(
    const float* __restrict__ W, const unsigned short* __restrict__ brow0,
    int kb, int K, int ldw, int ldb, int cW, bool nok,
    float wv[8], uintx4 bv[4])
{
    #pragma unroll
    for (int j = 0; j < 8; j++) {
        int k = kb + j;
        wv[j] = (nok && k < K) ? W[(size_t)k * ldw + cW] : 0.f;
    }
    #pragma unroll
    for (int s = 0; s < 4; s++)
        bv[s] = *(const uintx4*)(brow0 + (size_t)s * 16 * ldb + kb);
}

// Direct-streaming MFMA GEMM, no LDS, no barriers, depth-2 prefetch.
// part[by][n][b] = sum_{k in chunk} W[k][n] * Bm_bf16[b][k]
__global__ __launch_bounds__(256, 4) void mfma_gemm(
    const float* __restrict__ W, const unsigned short* __restrict__ Bm,
    float* __restrict__ part, int N, int Npad, int K, int ldw, int ldb,
    int kchunk, int ksteps)
{
    int tid  = threadIdx.x;
    int w    = tid >> 6;
    int lane = tid & 63;
    int q    = lane >> 4;
    int l15  = lane & 15;
    int n0   = blockIdx.x * 64;
    int k0   = blockIdx.y * kchunk;
    int cW   = n0 + 16 * w + l15;      // W column this lane reads (A-frag m index)
    bool nok = cW < N;
    int qk   = q * 8;

    floatx4 acc[4];
    #pragma unroll
    for (int s = 0; s < 4; s++) acc[s] = (floatx4){0.f, 0.f, 0.f, 0.f};

    const unsigned short* brow0 = Bm + (size_t)l15 * ldb;

    float  wv[2][8];
    uintx4 bv[2][4];
    load_step(W, brow0, k0 + qk, K, ldw, ldb, cW, nok, wv[0], bv[0]);
    {
        int s1 = (ksteps > 1) ? 1 : 0;
        load_step(W, brow0, k0 + s1 * 32 + qk, K, ldw, ldb, cW, nok, wv[1], bv[1]);
    }

    for (int st = 0; st < ksteps; st++) {
        int p   = st & 1;
        int stn = (st + 2 < ksteps) ? st + 2 : ksteps - 1;
        float  wt[8];
        uintx4 bt[4];
        load_step(W, brow0, k0 + stn * 32 + qk, K, ldw, ldb, cW, nok, wt, bt);

        short8 af;
        #pragma unroll
        for (int j = 0; j < 8; j++) af[j] = (short)f2bf(wv[p][j]);
        #pragma unroll
        for (int s = 0; s < 4; s++) {
            short8 bf8 = __builtin_bit_cast(short8, bv[p][s]);
            acc[s] = __builtin_amdgcn_mfma_f32_16x16x32_bf16(af, bf8, acc[s], 0, 0, 0);
        }

        #pragma unroll
        for (int j = 0; j < 8; j++) wv[p][j] = wt[j];
        #pragma unroll
        for (int s = 0; s < 4; s++) bv[p][s] = bt[s];
    }

    // D lane mapping: col=lane&15 (batch), row=q*4+r (n offset within 16)
    size_t base = (size_t)blockIdx.y * Npad * 64;
    int nrow = n0 + 16 * w + q * 4;
    #pragma unroll
    for (int s = 0; s < 4; s++) {
        #pragma unroll
        for (int r = 0; r < 4; r++)
            part[base + (size_t)(nrow + r) * 64 + s * 16 + l15] = acc[s][r];
    }
}

// reduce gemm1 partials + bias + exact GELU -> X bf16 [64][XLD] (concat exp_x, zero pad)
__global__ __launch_bounds__(256) void combine1(
    const float* __restrict__ part, const float* __restrict__ b1,
    const float* __restrict__ expx, unsigned short* __restrict__ X)
{
    int idx = blockIdx.x * 256 + threadIdx.x;   // 64*1664 threads
    int b = idx & 63;
    int n = idx >> 6;
    float v = 0.f;
    if (n < HID) {
        float s = 0.f;
        #pragma unroll
        for (int c = 0; c < KS1; c++)
            s += part[((size_t)c * NPAD1 + n) * 64 + b];
        s += b1[n];
        v = 0.5f * s * (1.0f + erff(s * 0.70710678118654752f));
    } else if (n < HID + EXP_SH) {
        v = expx[b * EXP_SH + (n - HID)];
    }
    X[(size_t)b * XLD + n] = f2bf(v);
}

// reduce gemm2 partials + bias + sigmoid, multiply by column max (reduced from 32 chunks)
__global__ __launch_bounds__(256) void final_k(
    const float* __restrict__ part2, const float* __restrict__ b2,
    const float* __restrict__ cm, float* __restrict__ out)
{
    int idx = blockIdx.x * 256 + threadIdx.x;   // 64*2048 threads
    int b = idx & 63;
    int j = idx >> 6;
    float s = 0.f;
    #pragma unroll
    for (int c = 0; c < KS2; c++)
        s += part2[((size_t)c * NBC + j) * 64 + b];
    s += b2[j];
    float sig = 1.0f / (1.0f + expf(-s));
    float m = 0.f;
    #pragma unroll
    for (int c = 0; c < CMCH; c++) m = fmaxf(m, cm[c * NBC + j]);
    out[(size_t)b * NBC + j] = sig * m;
}

extern "C" void kernel_launch(void* const* d_in, const int* in_sizes, int n_in,
                              void* d_out, int out_size, void* d_ws, size_t ws_size,
                              hipStream_t stream) {
    const float* gos  = (const float*)d_in[0];
    const float* expx = (const float*)d_in[1];
    const float* W1   = (const float*)d_in[2];
    const float* b1   = (const float*)d_in[3];
    const float* W2   = (const float*)d_in[4];
    const float* b2   = (const float*)d_in[5];
    const float* hpo  = (const float*)d_in[6];
    float* out = (float*)d_out;

    // workspace layout (16B-aligned offsets)
    char* ws = (char*)d_ws;
    unsigned short* gosB = (unsigned short*)ws;                          // 64*10240*2  = 1,310,720
    float* part1 = (float*)(ws + 1310720);                               // 40*1536*64*4 = 15,728,640
    unsigned short* X = (unsigned short*)(ws + 1310720 + 15728640);      // 64*1664*2   = 212,992
    float* part2 = (float*)(ws + 1310720 + 15728640 + 212992);           // 13*2048*64*4 = 6,815,744
    float* cm    = (float*)(ws + 1310720 + 15728640 + 212992 + 6815744); // 32*2048*4   = 262,144
    // total ~24.3 MB

    // 1) fused gos->bf16 convert + hpo partial column-max
    pre_k<<<576, 256, 0, stream>>>(gos, gosB, hpo, cm);

    // 2) GEMM1 partials: h_pre = gos @ W1  (N=1500, K=10000)
    mfma_gemm<<<dim3(NPAD1 / 64, KS1), 256, 0, stream>>>(
        W1, gosB, part1, HID, NPAD1, IN_SH, HID, GOSLD, KCH1, KST1);

    // 3) reduce + bias + gelu + concat exp_x -> X (bf16)
    combine1<<<(B64 * XLD) / 256, 256, 0, stream>>>(part1, b1, expx, X);

    // 4) GEMM2 partials: logits = X @ W2  (N=2048, K=1553)
    mfma_gemm<<<dim3(NBC / 64, KS2), 256, 0, stream>>>(
        W2, X, part2, NBC, NBC, K2, NBC, XLD, KCH2, KST2);

    // 5) reduce + bias + sigmoid + *colmax -> out
    final_k<<<(B64 * NBC) / 256, 256, 0, stream>>>(part2, b2, cm, out);
}

// Round 4
// 170.591 us; speedup vs baseline: 1.4693x; 1.4693x over previous
//
#include <hip/hip_runtime.h>
#include <math.h>

// Problem constants
#define B64 64
#define IN_SH 10000
#define GOSLD 10240         // gos bf16 padded leading dim (zero pad), mult of 32
#define EXP_SH 53
#define HID 1500
#define NPAD1 1536          // padded N for gemm1 partials
#define NBC 2048
#define K2 1553
#define XLD 1664            // X bf16 padded leading dim (13*128), zero padded
#define KS1 40              // split-K chunks gemm1
#define KCH1 256            // k per chunk (8 steps of 32)
#define KST1 8
#define KS2 13
#define KCH2 128            // 4 steps of 32
#define KST2 4
#define CMCH 32             // colmax row chunks

using short8  = __attribute__((ext_vector_type(8))) short;
using floatx4 = __attribute__((ext_vector_type(4))) float;
using uintx4  = __attribute__((ext_vector_type(4))) unsigned int;

__device__ __forceinline__ unsigned short f2bf(float f) {
    unsigned u = __float_as_uint(f);
    u += 0x7fffu + ((u >> 16) & 1u);   // RNE
    return (unsigned short)(u >> 16);
}

// Fused: [0,320) gos fp32->bf16 pad; [320,576) hpo partial column max (no atomics)
__global__ __launch_bounds__(256) void pre_k(const float* __restrict__ g,
                                             unsigned short* __restrict__ gb,
                                             const float* __restrict__ M,
                                             float* __restrict__ cm) {
    int bi = blockIdx.x;
    if (bi < 320) {
        int idx = bi * 256 + threadIdx.x;          // 64*1280 threads
        int b = idx / (GOSLD / 8);
        int k = (idx % (GOSLD / 8)) * 8;
        unsigned int o[4] = {0u, 0u, 0u, 0u};
        if (k < IN_SH) {
            const float* p = g + (size_t)b * IN_SH + k;
            #pragma unroll
            for (int i = 0; i < 4; i++) {
                float lo = p[2 * i], hi = p[2 * i + 1];
                o[i] = (unsigned)f2bf(lo) | ((unsigned)f2bf(hi) << 16);
            }
        }
        uintx4 v; v.x = o[0]; v.y = o[1]; v.z = o[2]; v.w = o[3];
        *(uintx4*)(gb + (size_t)b * GOSLD + k) = v;
    } else {
        int ci = bi - 320;                          // 256 blocks: 8 j-tiles x 32 row-chunks
        int j  = (ci & 7) * 256 + threadIdx.x;      // 0..2047
        int i0 = (ci >> 3) * 64;
        float m = 0.0f;
        #pragma unroll 16
        for (int i = i0; i < i0 + 64; i++)
            m = fmaxf(m, M[(size_t)i * NBC + j]);
        cm[(ci >> 3) * NBC + j] = m;
    }
}

// one pipeline stage's loads: W column slice (fp32, strided) + activation rows (bf16 x8)
__device__ __forceinline__ void load_step(
    const float* __restrict__ W, const unsigned short* __restrict__ brow0,
    int kb, int K, int ldw, int ldb, int cW, bool nok,
    float wv[8], uintx4 bv[4])
{
    #pragma unroll
    for (int j = 0; j < 8; j++) {
        int k = kb + j;
        wv[j] = (nok && k < K) ? W[(size_t)k * ldw + cW] : 0.f;
    }
    #pragma unroll
    for (int s = 0; s < 4; s++)
        bv[s] = *(const uintx4*)(brow0 + (size_t)s * 16 * ldb + kb);
}

// Direct-streaming MFMA GEMM, no LDS, no barriers, depth-2 prefetch.
// KSTEPS is a template param: full unroll makes all double-buffer indices
// compile-time -> arrays stay in VGPRs (runtime `st&1` demoted them to
// scratch in the previous round: 149 MB of spill traffic).
// part[by][n][b] = sum_{k in chunk} W[k][n] * Bm_bf16[b][k]
template<int KSTEPS>
__global__ __launch_bounds__(256) void mfma_gemm(
    const float* __restrict__ W, const unsigned short* __restrict__ Bm,
    float* __restrict__ part, int N, int Npad, int K, int ldw, int ldb,
    int kchunk)
{
    int tid  = threadIdx.x;
    int w    = tid >> 6;
    int lane = tid & 63;
    int q    = lane >> 4;
    int l15  = lane & 15;
    int n0   = blockIdx.x * 64;
    int k0   = blockIdx.y * kchunk;
    int cW   = n0 + 16 * w + l15;      // W column this lane reads (A-frag m index)
    bool nok = cW < N;
    int qk   = q * 8;

    floatx4 acc[4];
    #pragma unroll
    for (int s = 0; s < 4; s++) acc[s] = (floatx4){0.f, 0.f, 0.f, 0.f};

    const unsigned short* brow0 = Bm + (size_t)l15 * ldb;

    float  wv[2][8];
    uintx4 bv[2][4];
    load_step(W, brow0, k0 + qk, K, ldw, ldb, cW, nok, wv[0], bv[0]);
    if (KSTEPS > 1)
        load_step(W, brow0, k0 + 32 + qk, K, ldw, ldb, cW, nok, wv[1], bv[1]);

    #pragma unroll
    for (int st = 0; st < KSTEPS; st++) {
        const int p = st & 1;                       // compile-time after unroll
        float  wt[8];
        uintx4 bt[4];
        if (st + 2 < KSTEPS)
            load_step(W, brow0, k0 + (st + 2) * 32 + qk, K, ldw, ldb, cW, nok, wt, bt);

        short8 af;
        #pragma unroll
        for (int j = 0; j < 8; j++) af[j] = (short)f2bf(wv[p][j]);
        #pragma unroll
        for (int s = 0; s < 4; s++) {
            short8 bf8 = __builtin_bit_cast(short8, bv[p][s]);
            acc[s] = __builtin_amdgcn_mfma_f32_16x16x32_bf16(af, bf8, acc[s], 0, 0, 0);
        }

        if (st + 2 < KSTEPS) {
            #pragma unroll
            for (int j = 0; j < 8; j++) wv[p][j] = wt[j];
            #pragma unroll
            for (int s = 0; s < 4; s++) bv[p][s] = bt[s];
        }
    }

    // D lane mapping: col=lane&15 (batch), row=q*4+r (n offset within 16)
    size_t base = (size_t)blockIdx.y * Npad * 64;
    int nrow = n0 + 16 * w + q * 4;
    #pragma unroll
    for (int s = 0; s < 4; s++) {
        #pragma unroll
        for (int r = 0; r < 4; r++)
            part[base + (size_t)(nrow + r) * 64 + s * 16 + l15] = acc[s][r];
    }
}

// reduce gemm1 partials + bias + exact GELU -> X bf16 [64][XLD] (concat exp_x, zero pad)
__global__ __launch_bounds__(256) void combine1(
    const float* __restrict__ part, const float* __restrict__ b1,
    const float* __restrict__ expx, unsigned short* __restrict__ X)
{
    int idx = blockIdx.x * 256 + threadIdx.x;   // 64*1664 threads
    int b = idx & 63;
    int n = idx >> 6;
    float v = 0.f;
    if (n < HID) {
        float s = 0.f;
        #pragma unroll
        for (int c = 0; c < KS1; c++)
            s += part[((size_t)c * NPAD1 + n) * 64 + b];
        s += b1[n];
        v = 0.5f * s * (1.0f + erff(s * 0.70710678118654752f));
    } else if (n < HID + EXP_SH) {
        v = expx[b * EXP_SH + (n - HID)];
    }
    X[(size_t)b * XLD + n] = f2bf(v);
}

// reduce gemm2 partials + bias + sigmoid, multiply by column max (reduced from 32 chunks)
__global__ __launch_bounds__(256) void final_k(
    const float* __restrict__ part2, const float* __restrict__ b2,
    const float* __restrict__ cm, float* __restrict__ out)
{
    int idx = blockIdx.x * 256 + threadIdx.x;   // 64*2048 threads
    int b = idx & 63;
    int j = idx >> 6;
    float s = 0.f;
    #pragma unroll
    for (int c = 0; c < KS2; c++)
        s += part2[((size_t)c * NBC + j) * 64 + b];
    s += b2[j];
    float sig = 1.0f / (1.0f + expf(-s));
    float m = 0.f;
    #pragma unroll
    for (int c = 0; c < CMCH; c++) m = fmaxf(m, cm[c * NBC + j]);
    out[(size_t)b * NBC + j] = sig * m;
}

extern "C" void kernel_launch(void* const* d_in, const int* in_sizes, int n_in,
                              void* d_out, int out_size, void* d_ws, size_t ws_size,
                              hipStream_t stream) {
    const float* gos  = (const float*)d_in[0];
    const float* expx = (const float*)d_in[1];
    const float* W1   = (const float*)d_in[2];
    const float* b1   = (const float*)d_in[3];
    const float* W2   = (const float*)d_in[4];
    const float* b2   = (const float*)d_in[5];
    const float* hpo  = (const float*)d_in[6];
    float* out = (float*)d_out;

    // workspace layout (16B-aligned offsets)
    char* ws = (char*)d_ws;
    unsigned short* gosB = (unsigned short*)ws;                          // 64*10240*2  = 1,310,720
    float* part1 = (float*)(ws + 1310720);                               // 40*1536*64*4 = 15,728,640
    unsigned short* X = (unsigned short*)(ws + 1310720 + 15728640);      // 64*1664*2   = 212,992
    float* part2 = (float*)(ws + 1310720 + 15728640 + 212992);           // 13*2048*64*4 = 6,815,744
    float* cm    = (float*)(ws + 1310720 + 15728640 + 212992 + 6815744); // 32*2048*4   = 262,144
    // total ~24.3 MB

    // 1) fused gos->bf16 convert + hpo partial column-max
    pre_k<<<576, 256, 0, stream>>>(gos, gosB, hpo, cm);

    // 2) GEMM1 partials: h_pre = gos @ W1  (N=1500, K=10000)
    mfma_gemm<KST1><<<dim3(NPAD1 / 64, KS1), 256, 0, stream>>>(
        W1, gosB, part1, HID, NPAD1, IN_SH, HID, GOSLD, KCH1);

    // 3) reduce + bias + gelu + concat exp_x -> X (bf16)
    combine1<<<(B64 * XLD) / 256, 256, 0, stream>>>(part1, b1, expx, X);

    // 4) GEMM2 partials: logits = X @ W2  (N=2048, K=1553)
    mfma_gemm<KST2><<<dim3(NBC / 64, KS2), 256, 0, stream>>>(
        W2, X, part2, NBC, NBC, K2, NBC, XLD, KCH2);

    // 5) reduce + bias + sigmoid + *colmax -> out
    final_k<<<(B64 * NBC) / 256, 256, 0, stream>>>(part2, b2, cm, out);
}

// Round 5
// 167.618 us; speedup vs baseline: 1.4953x; 1.0177x over previous
//
#include <hip/hip_runtime.h>
#include <math.h>

// Problem constants
#define B64 64
#define IN_SH 10000
#define GOSLD 10240         // gos bf16 padded leading dim (zero pad), mult of 32
#define EXP_SH 53
#define HID 1500
#define NPAD1 1536          // padded N for gemm1 accumulator
#define NBC 2048
#define K2 1553
#define XLD 1664            // X bf16 padded leading dim (13*128), zero padded
#define KS1 40              // split-K chunks gemm1
#define KCH1 256            // k per chunk = KST1*32
#define KST1 8
#define KS2 13
#define KCH2 128            // = KST2*32
#define KST2 4
#define CMCH 32             // colmax row chunks
#define ACCF (NPAD1 * B64 + NBC * B64)   // floats to zero: 98304 + 131072 = 229376

using short8  = __attribute__((ext_vector_type(8))) short;
using floatx4 = __attribute__((ext_vector_type(4))) float;
using uintx4  = __attribute__((ext_vector_type(4))) unsigned int;

__device__ __forceinline__ unsigned short f2bf(float f) {
    unsigned u = __float_as_uint(f);
    u += 0x7fffu + ((u >> 16) & 1u);   // RNE
    return (unsigned short)(u >> 16);
}

// Fused: [0,320) gos fp32->bf16 pad; [320,576) hpo partial column max;
//        [576,584) zero the fp32 accumulators (h_pre + logits, contiguous).
__global__ __launch_bounds__(256) void pre_k(const float* __restrict__ g,
                                             unsigned short* __restrict__ gb,
                                             const float* __restrict__ M,
                                             float* __restrict__ cm,
                                             float* __restrict__ accz) {
    int bi = blockIdx.x;
    if (bi < 320) {
        int idx = bi * 256 + threadIdx.x;          // 64*1280 threads
        int b = idx / (GOSLD / 8);
        int k = (idx % (GOSLD / 8)) * 8;
        unsigned int o[4] = {0u, 0u, 0u, 0u};
        if (k < IN_SH) {
            const float* p = g + (size_t)b * IN_SH + k;
            #pragma unroll
            for (int i = 0; i < 4; i++) {
                float lo = p[2 * i], hi = p[2 * i + 1];
                o[i] = (unsigned)f2bf(lo) | ((unsigned)f2bf(hi) << 16);
            }
        }
        uintx4 v; v.x = o[0]; v.y = o[1]; v.z = o[2]; v.w = o[3];
        *(uintx4*)(gb + (size_t)b * GOSLD + k) = v;
    } else if (bi < 576) {
        int ci = bi - 320;                          // 256 blocks: 8 j-tiles x 32 row-chunks
        int j  = (ci & 7) * 256 + threadIdx.x;      // 0..2047
        int i0 = (ci >> 3) * 64;
        float m = 0.0f;
        #pragma unroll 16
        for (int i = i0; i < i0 + 64; i++)
            m = fmaxf(m, M[(size_t)i * NBC + j]);
        cm[(ci >> 3) * NBC + j] = m;
    } else {
        // zero 229376 floats with 8 blocks: 2048 threads * 28 float4
        int t = (bi - 576) * 256 + threadIdx.x;    // 0..2047
        floatx4 z = (floatx4){0.f, 0.f, 0.f, 0.f};
        #pragma unroll
        for (int i = 0; i < 28; i++)
            *(floatx4*)(accz + (size_t)(i * 2048 + t) * 4) = z;
    }
}

// one pipeline stage's loads: W column slice (fp32, strided) + activation rows (bf16 x8)
__device__ __forceinline__ void load_step(
    const float* __restrict__ W, const unsigned short* __restrict__ brow0,
    int kb, int K, int ldw, int ldb, int cW, bool nok,
    float wv[8], uintx4 bv[4])
{
    #pragma unroll
    for (int j = 0; j < 8; j++) {
        int k = kb + j;
        wv[j] = (nok && k < K) ? W[(size_t)k * ldw + cW] : 0.f;
    }
    #pragma unroll
    for (int s = 0; s < 4; s++)
        bv[s] = *(const uintx4*)(brow0 + (size_t)s * 16 * ldb + kb);
}

// Direct-streaming MFMA GEMM, no LDS, no barriers, depth-2 prefetch,
// fp32 atomicAdd accumulation into acc[n*64+b] (no split-K partial buffers).
// KSTEPS template: full unroll keeps double-buffer arrays in VGPRs.
template<int KSTEPS>
__global__ __launch_bounds__(256) void mfma_gemm(
    const float* __restrict__ W, const unsigned short* __restrict__ Bm,
    float* __restrict__ accbuf, int N, int K, int ldw, int ldb, int kchunk)
{
    int tid  = threadIdx.x;
    int w    = tid >> 6;
    int lane = tid & 63;
    int q    = lane >> 4;
    int l15  = lane & 15;
    int n0   = blockIdx.x * 64;
    int k0   = blockIdx.y * kchunk;
    int cW   = n0 + 16 * w + l15;      // W column this lane reads (A-frag m index)
    bool nok = cW < N;
    int qk   = q * 8;

    floatx4 acc[4];
    #pragma unroll
    for (int s = 0; s < 4; s++) acc[s] = (floatx4){0.f, 0.f, 0.f, 0.f};

    const unsigned short* brow0 = Bm + (size_t)l15 * ldb;

    float  wv[2][8];
    uintx4 bv[2][4];
    load_step(W, brow0, k0 + qk, K, ldw, ldb, cW, nok, wv[0], bv[0]);
    if (KSTEPS > 1)
        load_step(W, brow0, k0 + 32 + qk, K, ldw, ldb, cW, nok, wv[1], bv[1]);

    #pragma unroll
    for (int st = 0; st < KSTEPS; st++) {
        const int p = st & 1;                       // compile-time after unroll
        float  wt[8];
        uintx4 bt[4];
        if (st + 2 < KSTEPS)
            load_step(W, brow0, k0 + (st + 2) * 32 + qk, K, ldw, ldb, cW, nok, wt, bt);

        short8 af;
        #pragma unroll
        for (int j = 0; j < 8; j++) af[j] = (short)f2bf(wv[p][j]);
        #pragma unroll
        for (int s = 0; s < 4; s++) {
            short8 bf8 = __builtin_bit_cast(short8, bv[p][s]);
            acc[s] = __builtin_amdgcn_mfma_f32_16x16x32_bf16(af, bf8, acc[s], 0, 0, 0);
        }

        if (st + 2 < KSTEPS) {
            #pragma unroll
            for (int j = 0; j < 8; j++) wv[p][j] = wt[j];
            #pragma unroll
            for (int s = 0; s < 4; s++) bv[p][s] = bt[s];
        }
    }

    // D lane mapping: col=lane&15 (batch), row=q*4+r (n offset within 16)
    int nrow = n0 + 16 * w + q * 4;
    #pragma unroll
    for (int s = 0; s < 4; s++) {
        #pragma unroll
        for (int r = 0; r < 4; r++)
            atomicAdd(&accbuf[(size_t)(nrow + r) * 64 + s * 16 + l15], acc[s][r]);
    }
}

// bias + exact GELU on h_pre -> X bf16 [64][XLD] (concat exp_x, zero pad)
__global__ __launch_bounds__(256) void combine1(
    const float* __restrict__ hpre, const float* __restrict__ b1,
    const float* __restrict__ expx, unsigned short* __restrict__ X)
{
    int idx = blockIdx.x * 256 + threadIdx.x;   // 64*1664 threads
    int b = idx & 63;
    int n = idx >> 6;
    float v = 0.f;
    if (n < HID) {
        float s = hpre[(size_t)n * 64 + b] + b1[n];
        v = 0.5f * s * (1.0f + erff(s * 0.70710678118654752f));
    } else if (n < HID + EXP_SH) {
        v = expx[b * EXP_SH + (n - HID)];
    }
    X[(size_t)b * XLD + n] = f2bf(v);
}

// bias + sigmoid on logits, multiply by column max (reduced from 32 chunks)
__global__ __launch_bounds__(256) void final_k(
    const float* __restrict__ logits, const float* __restrict__ b2,
    const float* __restrict__ cm, float* __restrict__ out)
{
    int idx = blockIdx.x * 256 + threadIdx.x;   // 64*2048 threads
    int b = idx & 63;
    int j = idx >> 6;
    float s = logits[(size_t)j * 64 + b] + b2[j];
    float sig = 1.0f / (1.0f + expf(-s));
    float m = 0.f;
    #pragma unroll
    for (int c = 0; c < CMCH; c++) m = fmaxf(m, cm[c * NBC + j]);
    out[(size_t)b * NBC + j] = sig * m;
}

extern "C" void kernel_launch(void* const* d_in, const int* in_sizes, int n_in,
                              void* d_out, int out_size, void* d_ws, size_t ws_size,
                              hipStream_t stream) {
    const float* gos  = (const float*)d_in[0];
    const float* expx = (const float*)d_in[1];
    const float* W1   = (const float*)d_in[2];
    const float* b1   = (const float*)d_in[3];
    const float* W2   = (const float*)d_in[4];
    const float* b2   = (const float*)d_in[5];
    const float* hpo  = (const float*)d_in[6];
    float* out = (float*)d_out;

    // workspace layout (16B-aligned offsets)
    char* ws = (char*)d_ws;
    unsigned short* gosB = (unsigned short*)ws;                    // 64*10240*2 = 1,310,720
    float* hpre   = (float*)(ws + 1310720);                        // 1536*64*4  =   393,216
    float* logits = (float*)(ws + 1310720 + 393216);               // 2048*64*4  =   524,288  (contiguous with hpre)
    unsigned short* X = (unsigned short*)(ws + 1310720 + 393216 + 524288);   // 64*1664*2 = 212,992
    float* cm = (float*)(ws + 1310720 + 393216 + 524288 + 212992); // 32*2048*4  =   262,144
    // total ~2.7 MB

    // 1) fused: gos->bf16 | hpo partial column-max | zero accumulators
    pre_k<<<584, 256, 0, stream>>>(gos, gosB, hpo, cm, hpre);

    // 2) GEMM1: h_pre += gos @ W1  (N=1500, K=10000), atomic split-K
    mfma_gemm<KST1><<<dim3(NPAD1 / 64, KS1), 256, 0, stream>>>(
        W1, gosB, hpre, HID, IN_SH, HID, GOSLD, KCH1);

    // 3) bias + gelu + concat exp_x -> X (bf16)
    combine1<<<(B64 * XLD) / 256, 256, 0, stream>>>(hpre, b1, expx, X);

    // 4) GEMM2: logits += X @ W2  (N=2048, K=1553), atomic split-K
    mfma_gemm<KST2><<<dim3(NBC / 64, KS2), 256, 0, stream>>>(
        W2, X, logits, NBC, K2, NBC, XLD, KCH2);

    // 5) bias + sigmoid + *colmax -> out
    final_k<<<(B64 * NBC) / 256, 256, 0, stream>>>(logits, b2, cm, out);
}